// Round 1
// baseline (9812.949 us; speedup 1.0000x reference)
//
#include <hip/hip_runtime.h>
#include <cmath>
#include <stdint.h>

#define BB 32
#define TT 24
#define NN 1024
#define FF 2
#define UU 16
#define HH 32
#define TFN 31
#define NWG 256

typedef __attribute__((ext_vector_type(8))) short bf16x8;
typedef __attribute__((ext_vector_type(4))) float f32x4;
typedef unsigned short u16;
typedef unsigned int   u32;

// Y double buffer: [2][B][32 rows][1024] bf16, bytes XOR-swizzled within each
// 2048-B row:  byte(j,k) = j*2048 + ((2k) ^ ((j&7)<<4))
__device__ __align__(16) u16 g_Y[2][BB][32*NN];
__device__ float g_c2[BB*FF];
__device__ __align__(64) u32 g_barcnt;

__device__ __forceinline__ float sigmf(float x){ return 1.f/(1.f+expf(-x)); }
__device__ __forceinline__ u16 f2bf(float f){      // RNE fp32 -> bf16
  u32 u = __float_as_uint(f);
  return (u16)((u + 0x7fffu + ((u>>16)&1u)) >> 16);
}
__device__ __forceinline__ void ywr(u16* Yb, int j, int n, float s){
  *(u16*)((char*)Yb + (j<<11) + (((n<<1)) ^ ((j&7)<<4))) = f2bf(s);
}

// ---- inline monotonic grid barrier (counter reset each launch by k_lstm) ----
__device__ __forceinline__ void gridbar(u32 target){
  __threadfence();                       // release (agent scope)
  __syncthreads();
  if (threadIdx.x == 0){
    __hip_atomic_fetch_add(&g_barcnt, 1u, __ATOMIC_RELAXED, __HIP_MEMORY_SCOPE_AGENT);
    while (__hip_atomic_load(&g_barcnt, __ATOMIC_RELAXED, __HIP_MEMORY_SCOPE_AGENT) < target)
      __builtin_amdgcn_s_sleep(2);
  }
  __syncthreads();
  __threadfence();                       // acquire (agent scope)
}

// ---- stage W rows (W*2048 bytes) of swizzled Y linearly into LDS ----
template<int W>
__device__ __forceinline__ void stageY(const u16* __restrict__ Yb, u16* Ys, int tid){
#pragma unroll
  for (int q=0;q<W/4;q++){
    *(uint4*)((char*)Ys + q*8192 + tid*16) =
      *(const uint4*)((const char*)Yb + q*8192 + tid*16);
  }
}

// swizzled address decomposition: (c*64 + quad*16) ^ ((m&7)<<4)
//   = ((quad ^ (m&3))<<4) + ((c ^ ((m>>2)&1))<<6)   -> base0 + ((c^cflip)<<6)
__device__ __forceinline__ void mm32(const bf16x8 (&areg)[32], const u16* Ys,
                                     int base0, int cflip, f32x4& a0, f32x4& a1){
#pragma unroll
  for (int c=0;c<32;c++){
    int off = base0 + ((c ^ cflip) << 6);
    bf16x8 b0 = *(const bf16x8*)((const char*)Ys + off);
    bf16x8 b1 = *(const bf16x8*)((const char*)Ys + off + 32768);
    a0 = __builtin_amdgcn_mfma_f32_16x16x32_bf16(areg[c], b0, a0, 0, 0, 0);
    a1 = __builtin_amdgcn_mfma_f32_16x16x32_bf16(areg[c], b1, a1, 0, 0, 0);
  }
}
__device__ __forceinline__ void mm16(const bf16x8 (&areg)[32], const u16* Ys,
                                     int base0, int cflip, f32x4& a0){
#pragma unroll
  for (int c=0;c<32;c++){
    int off = base0 + ((c ^ cflip) << 6);
    bf16x8 b0 = *(const bf16x8*)((const char*)Ys + off);
    a0 = __builtin_amdgcn_mfma_f32_16x16x32_bf16(areg[c], b0, a0, 0, 0, 0);
  }
}

// ---------------- LSTM + ff + const2 (also resets barrier counter) ----------------
__global__ __launch_bounds__(128)
void k_lstm(const float* __restrict__ trend, const float* __restrict__ tfeat,
            const float* __restrict__ Wih0, const float* __restrict__ Whh0,
            const float* __restrict__ bih0, const float* __restrict__ bhh0,
            const float* __restrict__ Wih1, const float* __restrict__ Whh1,
            const float* __restrict__ bih1, const float* __restrict__ bhh1,
            const float* __restrict__ ffW, const float* __restrict__ ffb,
            const float* __restrict__ gcnW) {
  __shared__ float h[HH], c[HH], g[4*HH], hs0[TT][HH], tr[HH], fe[HH];
  int b = blockIdx.x, tid = threadIdx.x;
  if (b == 0 && tid == 0) g_barcnt = 0u;
  if (tid < HH) { h[tid]=0.f; c[tid]=0.f; }
  __syncthreads();
  for (int t=0;t<TT;t++) {
    float x0 = trend[(b*TT+t)*FF+0], x1 = trend[(b*TT+t)*FF+1];
    float gv = bih0[tid] + bhh0[tid] + x0*Wih0[tid*FF+0] + x1*Wih0[tid*FF+1];
#pragma unroll
    for (int k=0;k<HH;k++) gv += h[k]*Whh0[tid*HH+k];
    g[tid] = gv;
    __syncthreads();
    if (tid < HH) {
      float ii = sigmf(g[tid]), ff = sigmf(g[HH+tid]);
      float gg = tanhf(g[2*HH+tid]), oo = sigmf(g[3*HH+tid]);
      float cn = ff*c[tid] + ii*gg;
      c[tid] = cn;
      float hn = oo*tanhf(cn);
      h[tid] = hn;
      hs0[t][tid] = hn;
    }
    __syncthreads();
  }
  if (tid < HH) { h[tid]=0.f; c[tid]=0.f; }
  __syncthreads();
  for (int t=0;t<TT;t++) {
    float gv = bih1[tid] + bhh1[tid];
#pragma unroll
    for (int k=0;k<HH;k++) gv += hs0[t][k]*Wih1[tid*HH+k];
#pragma unroll
    for (int k=0;k<HH;k++) gv += h[k]*Whh1[tid*HH+k];
    g[tid] = gv;
    __syncthreads();
    if (tid < HH) {
      float ii = sigmf(g[tid]), ff = sigmf(g[HH+tid]);
      float gg = tanhf(g[2*HH+tid]), oo = sigmf(g[3*HH+tid]);
      float cn = ff*c[tid] + ii*gg;
      c[tid] = cn;
      h[tid] = oo*tanhf(cn);
    }
    __syncthreads();
  }
  if (tid < HH) {
    tr[tid] = h[tid];
    float fv = ffb[tid];
#pragma unroll
    for (int j=0;j<TFN;j++) fv += tfeat[b*TFN+j]*ffW[tid*TFN+j];
    fe[tid] = fmaxf(fv, 0.f);
  }
  __syncthreads();
  if (tid < FF) {
    float s = 0.f;
#pragma unroll
    for (int j=0;j<HH;j++) s += tr[j]*gcnW[tid*80+16+j];
#pragma unroll
    for (int j=0;j<HH;j++) s += fe[j]*gcnW[tid*80+48+j];
    g_c2[b*FF+tid] = s;
  }
}

// ---------------- persistent cooperative kernel: whole recurrence ----------------
struct KP {
  const float *recent, *A;
  const float *g1rW,*g1rb,*g1uW,*g1ub,*g1cW,*g1cb;
  const float *g2rW,*g2rb,*g2uW,*g2ub,*g2cW,*g2cb;
  const float *gcnW,*gcnb;
  float *out;
};

__global__ __launch_bounds__(512, 2)
void k_main(KP p){
  __shared__ __align__(16) u16 Ys[32*NN];   // 64 KB swizzled Y tile
  __shared__ float Ps [128][33];
  __shared__ float h1s[128][17];
  __shared__ float h2s[128][17];
  __shared__ float us_[128][17];
  __shared__ float rhs[128][17];

  const int wg = blockIdx.x;
  const int b = wg >> 3, i0 = (wg & 7) << 7;
  const int tid = threadIdx.x;
  const int v = tid >> 6, lane = tid & 63, m = lane & 15, quad = lane >> 4;
  const int rloc = v << 4;
  const int row = tid >> 2, jj = tid & 3;   // epilogue mapping: 4 thr/row
  const int n = i0 + row;
  const int base0 = m*2048 + ((quad ^ (m & 3)) << 4);
  const int cflip = (m >> 2) & 1;

  // ---- prologue: park A rows in registers (bf16), read fp32 A once ----
  bf16x8 areg[32];
  {
    const float* Ab = p.A + ((size_t)(b*NN + i0 + rloc + m))*NN + quad*8;
#pragma unroll
    for (int c=0;c<32;c++){
      float4 f0 = *(const float4*)(Ab + c*32);
      float4 f1 = *(const float4*)(Ab + c*32 + 4);
      bf16x8 tv;
      tv[0]=(short)f2bf(f0.x); tv[1]=(short)f2bf(f0.y);
      tv[2]=(short)f2bf(f0.z); tv[3]=(short)f2bf(f0.w);
      tv[4]=(short)f2bf(f1.x); tv[5]=(short)f2bf(f1.y);
      tv[6]=(short)f2bf(f1.z); tv[7]=(short)f2bf(f1.w);
      areg[c] = tv;
    }
  }

  // zero hidden state
#pragma unroll
  for (int q=0;q<4;q++){ h1s[row][jj*4+q]=0.f; h2s[row][jj*4+q]=0.f; }

  // ---- Yru1(t=0) = [rW1|uW1]·[x(0), 0]  -> buf 0 ----
  {
    const float* xr = p.recent + (((size_t)b*TT)*NN + n)*FF;
    float x0 = xr[0], x1 = xr[1];
    u16* Yb = g_Y[0][b];
#pragma unroll
    for (int m2=0;m2<8;m2++){
      int j = jj*8 + m2;
      const float* W = (j<16) ? (p.g1rW + j*18) : (p.g1uW + (j-16)*18);
      ywr(Yb, j, n, x0*W[0] + x1*W[1]);
    }
  }
  u32 gen = 0;
  gridbar((++gen)*NWG);

  int buf = 0;
  for (int t=0;t<TT;t++){
    // ======== sweep 1: r,u cell1 (width 32) ========
    stageY<32>(g_Y[buf][b], Ys, tid);
    __syncthreads();
    {
      f32x4 a0={0.f,0.f,0.f,0.f}, a1={0.f,0.f,0.f,0.f};
      mm32(areg, Ys, base0, cflip, a0, a1);
#pragma unroll
      for (int r=0;r<4;r++){
        Ps[rloc + quad*4 + r][m]    = a0[r];
        Ps[rloc + quad*4 + r][16+m] = a1[r];
      }
    }
    __syncthreads();
#pragma unroll
    for (int q=0;q<4;q++){
      int j = jj*4+q;
      float rv = sigmf(Ps[row][j]    + p.g1rb[j]);
      float uv = sigmf(Ps[row][16+j] + p.g1ub[j]);
      us_[row][j] = uv;
      rhs[row][j] = rv * h1s[row][j];
    }
    __syncthreads();
    {
      const float* xr = p.recent + (((size_t)b*TT + t)*NN + n)*FF;
      float x0 = xr[0], x1 = xr[1];
      u16* Yb = g_Y[buf^1][b];
#pragma unroll
      for (int q=0;q<4;q++){
        int j = jj*4+q;
        const float* W = p.g1cW + j*18;
        float s = fmaf(x0, W[0], x1*W[1]);
#pragma unroll
        for (int f=0;f<16;f++) s = fmaf(rhs[row][f], W[2+f], s);
        ywr(Yb, j, n, s);
      }
    }
    gridbar((++gen)*NWG); buf ^= 1;

    // ======== sweep 2: c cell1 -> h1; produce Yru2 (width 16) ========
    stageY<16>(g_Y[buf][b], Ys, tid);
    __syncthreads();
    {
      f32x4 a0={0.f,0.f,0.f,0.f};
      mm16(areg, Ys, base0, cflip, a0);
#pragma unroll
      for (int r=0;r<4;r++) Ps[rloc + quad*4 + r][m] = a0[r];
    }
    __syncthreads();
#pragma unroll
    for (int q=0;q<4;q++){
      int j = jj*4+q;
      float cv = tanhf(Ps[row][j] + p.g1cb[j]);
      float uv = us_[row][j];
      h1s[row][j] = uv*h1s[row][j] + (1.f-uv)*cv;
    }
    __syncthreads();
    {
      u16* Yb = g_Y[buf^1][b];
#pragma unroll
      for (int m2=0;m2<8;m2++){
        int j = jj*8 + m2;
        const float* W = (j<16) ? (p.g2rW + j*32) : (p.g2uW + (j-16)*32);
        float s = 0.f;
#pragma unroll
        for (int f=0;f<16;f++) s = fmaf(h1s[row][f], W[f],    s);
#pragma unroll
        for (int f=0;f<16;f++) s = fmaf(h2s[row][f], W[16+f], s);
        ywr(Yb, j, n, s);
      }
    }
    gridbar((++gen)*NWG); buf ^= 1;

    // ======== sweep 3: r,u cell2 (width 32) ========
    stageY<32>(g_Y[buf][b], Ys, tid);
    __syncthreads();
    {
      f32x4 a0={0.f,0.f,0.f,0.f}, a1={0.f,0.f,0.f,0.f};
      mm32(areg, Ys, base0, cflip, a0, a1);
#pragma unroll
      for (int r=0;r<4;r++){
        Ps[rloc + quad*4 + r][m]    = a0[r];
        Ps[rloc + quad*4 + r][16+m] = a1[r];
      }
    }
    __syncthreads();
#pragma unroll
    for (int q=0;q<4;q++){
      int j = jj*4+q;
      float rv = sigmf(Ps[row][j]    + p.g2rb[j]);
      float uv = sigmf(Ps[row][16+j] + p.g2ub[j]);
      us_[row][j] = uv;
      rhs[row][j] = rv * h2s[row][j];
    }
    __syncthreads();
    {
      u16* Yb = g_Y[buf^1][b];
#pragma unroll
      for (int q=0;q<4;q++){
        int j = jj*4+q;
        const float* W = p.g2cW + j*32;
        float s = 0.f;
#pragma unroll
        for (int f=0;f<16;f++) s = fmaf(h1s[row][f], W[f],    s);
#pragma unroll
        for (int f=0;f<16;f++) s = fmaf(rhs[row][f], W[16+f], s);
        ywr(Yb, j, n, s);
      }
    }
    gridbar((++gen)*NWG); buf ^= 1;

    // ======== sweep 4: c cell2 -> h2; Yru1(t+1) | Ysmall (width 16) ========
    stageY<16>(g_Y[buf][b], Ys, tid);
    __syncthreads();
    {
      f32x4 a0={0.f,0.f,0.f,0.f};
      mm16(areg, Ys, base0, cflip, a0);
#pragma unroll
      for (int r=0;r<4;r++) Ps[rloc + quad*4 + r][m] = a0[r];
    }
    __syncthreads();
#pragma unroll
    for (int q=0;q<4;q++){
      int j = jj*4+q;
      float cv = tanhf(Ps[row][j] + p.g2cb[j]);
      float uv = us_[row][j];
      h2s[row][j] = uv*h2s[row][j] + (1.f-uv)*cv;
    }
    __syncthreads();
    if (t < TT-1){
      const float* xr = p.recent + (((size_t)b*TT + t + 1)*NN + n)*FF;
      float x0 = xr[0], x1 = xr[1];
      u16* Yb = g_Y[buf^1][b];
#pragma unroll
      for (int m2=0;m2<8;m2++){
        int j = jj*8 + m2;
        const float* W = (j<16) ? (p.g1rW + j*18) : (p.g1uW + (j-16)*18);
        float s = fmaf(x0, W[0], x1*W[1]);
#pragma unroll
        for (int f=0;f<16;f++) s = fmaf(h1s[row][f], W[2+f], s);
        ywr(Yb, j, n, s);
      }
    } else {
      u16* Yb = g_Y[buf^1][b];
#pragma unroll
      for (int q=0;q<4;q++){
        int j = jj*4+q;
        float s = 0.f;
        if (j < FF){
          s = g_c2[b*FF + j];
#pragma unroll
          for (int f=0;f<16;f++) s = fmaf(h2s[row][f], p.gcnW[j*80+f], s);
        }
        ywr(Yb, j, n, s);
      }
    }
    gridbar((++gen)*NWG); buf ^= 1;
  }

  // ======== final: out = tanh(A @ Ysmall + gcnb) ========
  stageY<16>(g_Y[buf][b], Ys, tid);
  __syncthreads();
  {
    f32x4 a0={0.f,0.f,0.f,0.f};
    mm16(areg, Ys, base0, cflip, a0);
    if (m < FF){
      float bb = p.gcnb[m];
#pragma unroll
      for (int r=0;r<4;r++){
        int nn = i0 + rloc + quad*4 + r;
        p.out[((size_t)b*NN + nn)*FF + m] = tanhf(a0[r] + bb);
      }
    }
  }
}

extern "C" void kernel_launch(void* const* d_in, const int* in_sizes, int n_in,
                              void* d_out, int out_size, void* d_ws, size_t ws_size,
                              hipStream_t stream) {
  (void)in_sizes; (void)n_in; (void)d_ws; (void)ws_size; (void)out_size;
  const float* recent = (const float*)d_in[0];
  const float* trend  = (const float*)d_in[1];
  const float* A      = (const float*)d_in[2];
  const float* tfeat  = (const float*)d_in[3];
  const float* g1rW = (const float*)d_in[4];  const float* g1rb = (const float*)d_in[5];
  const float* g1uW = (const float*)d_in[6];  const float* g1ub = (const float*)d_in[7];
  const float* g1cW = (const float*)d_in[8];  const float* g1cb = (const float*)d_in[9];
  const float* g2rW = (const float*)d_in[10]; const float* g2rb = (const float*)d_in[11];
  const float* g2uW = (const float*)d_in[12]; const float* g2ub = (const float*)d_in[13];
  const float* g2cW = (const float*)d_in[14]; const float* g2cb = (const float*)d_in[15];
  const float* Wih0 = (const float*)d_in[16]; const float* Whh0 = (const float*)d_in[17];
  const float* bih0 = (const float*)d_in[18]; const float* bhh0 = (const float*)d_in[19];
  const float* Wih1 = (const float*)d_in[20]; const float* Whh1 = (const float*)d_in[21];
  const float* bih1 = (const float*)d_in[22]; const float* bhh1 = (const float*)d_in[23];
  const float* ffW  = (const float*)d_in[24]; const float* ffb  = (const float*)d_in[25];
  const float* gcnW = (const float*)d_in[26]; const float* gcnb = (const float*)d_in[27];
  float* out = (float*)d_out;

  // resets barrier counter + computes g_c2; ordered before k_main on the stream
  k_lstm<<<BB, 128, 0, stream>>>(trend, tfeat, Wih0, Whh0, bih0, bhh0,
                                 Wih1, Whh1, bih1, bhh1, ffW, ffb, gcnW);

  KP kp;
  kp.recent = recent; kp.A = A;
  kp.g1rW=g1rW; kp.g1rb=g1rb; kp.g1uW=g1uW; kp.g1ub=g1ub; kp.g1cW=g1cW; kp.g1cb=g1cb;
  kp.g2rW=g2rW; kp.g2rb=g2rb; kp.g2uW=g2uW; kp.g2ub=g2ub; kp.g2cW=g2cW; kp.g2cb=g2cb;
  kp.gcnW=gcnW; kp.gcnb=gcnb; kp.out=out;
  void* args[] = { (void*)&kp };
  hipLaunchCooperativeKernel((const void*)k_main, dim3(NWG), dim3(512), args, 0, stream);
}

// Round 2
// 4000.225 us; speedup vs baseline: 2.4531x; 2.4531x over previous
//
#include <hip/hip_runtime.h>
#include <cmath>
#include <stdint.h>

#define BB 32
#define TT 24
#define NN 1024
#define FF 2
#define UU 16
#define HH 32
#define TFN 31
#define NWG 256

typedef __attribute__((ext_vector_type(8))) short bf16x8;
typedef __attribute__((ext_vector_type(4))) float f32x4;
typedef unsigned short u16;
typedef unsigned int   u32;

// Y double buffer: [2][B][32 rows][1024] bf16, bytes XOR-swizzled within each
// 2048-B row:  byte(j,k) = j*2048 + ((2k) ^ ((j&7)<<4))
__device__ __align__(16) u16 g_Y[2][BB][32*NN];
__device__ float g_c2[BB*FF];
// per-b barrier counters, one 256-B line each (8 arrivals per barrier)
__device__ __align__(256) u32 g_bar[BB][64];

__device__ __forceinline__ float sigmf(float x){ return 1.f/(1.f+expf(-x)); }
__device__ __forceinline__ u16 f2bf(float f){      // RNE fp32 -> bf16
  u32 u = __float_as_uint(f);
  return (u16)((u + 0x7fffu + ((u>>16)&1u)) >> 16);
}
__device__ __forceinline__ void ywr(u16* Yb, int j, int n, float s){
  *(u16*)((char*)Yb + (j<<11) + (((n<<1)) ^ ((j&7)<<4))) = f2bf(s);
}

// ---- per-b barrier: 8 WGs of one batch; monotonic generation target ----
// release: tid0 RMW(RELEASE) publishes WG's L2-resident stores (syncthreads
// already drained them to L2). acquire: one ACQUIRE load per thread after the
// exit sync invalidates stale L1/L2 lines before Y staging.
__device__ __forceinline__ void bbar(u32* cnt, u32 target){
  __syncthreads();
  if (threadIdx.x == 0){
    __hip_atomic_fetch_add(cnt, 1u, __ATOMIC_RELEASE, __HIP_MEMORY_SCOPE_AGENT);
    while (__hip_atomic_load(cnt, __ATOMIC_RELAXED, __HIP_MEMORY_SCOPE_AGENT) < target)
      __builtin_amdgcn_s_sleep(1);
  }
  __syncthreads();
  u32 x = __hip_atomic_load(cnt, __ATOMIC_ACQUIRE, __HIP_MEMORY_SCOPE_AGENT);
  asm volatile("" :: "v"(x));
}

// ---- stage W rows (W*2048 bytes) of swizzled Y linearly into LDS ----
template<int W>
__device__ __forceinline__ void stageY(const u16* __restrict__ Yb, u16* Ys, int tid){
#pragma unroll
  for (int q=0;q<W/4;q++){
    *(uint4*)((char*)Ys + q*8192 + tid*16) =
      *(const uint4*)((const char*)Yb + q*8192 + tid*16);
  }
}

// swizzled address decomposition: (c*64 + quad*16) ^ ((m&7)<<4)
//   = ((quad ^ (m&3))<<4) + ((c ^ ((m>>2)&1))<<6)   -> base0 + ((c^cflip)<<6)
__device__ __forceinline__ void mm32(const bf16x8 (&areg)[32], const u16* Ys,
                                     int base0, int cflip, f32x4& a0, f32x4& a1){
#pragma unroll
  for (int c=0;c<32;c++){
    int off = base0 + ((c ^ cflip) << 6);
    bf16x8 b0 = *(const bf16x8*)((const char*)Ys + off);
    bf16x8 b1 = *(const bf16x8*)((const char*)Ys + off + 32768);
    a0 = __builtin_amdgcn_mfma_f32_16x16x32_bf16(areg[c], b0, a0, 0, 0, 0);
    a1 = __builtin_amdgcn_mfma_f32_16x16x32_bf16(areg[c], b1, a1, 0, 0, 0);
  }
}
__device__ __forceinline__ void mm16(const bf16x8 (&areg)[32], const u16* Ys,
                                     int base0, int cflip, f32x4& a0){
#pragma unroll
  for (int c=0;c<32;c++){
    int off = base0 + ((c ^ cflip) << 6);
    bf16x8 b0 = *(const bf16x8*)((const char*)Ys + off);
    a0 = __builtin_amdgcn_mfma_f32_16x16x32_bf16(areg[c], b0, a0, 0, 0, 0);
  }
}

// ---------------- LSTM + ff + const2 (also resets barrier counters) ----------------
__global__ __launch_bounds__(128)
void k_lstm(const float* __restrict__ trend, const float* __restrict__ tfeat,
            const float* __restrict__ Wih0, const float* __restrict__ Whh0,
            const float* __restrict__ bih0, const float* __restrict__ bhh0,
            const float* __restrict__ Wih1, const float* __restrict__ Whh1,
            const float* __restrict__ bih1, const float* __restrict__ bhh1,
            const float* __restrict__ ffW, const float* __restrict__ ffb,
            const float* __restrict__ gcnW) {
  __shared__ float h[HH], c[HH], g[4*HH], hs0[TT][HH], tr[HH], fe[HH];
  int b = blockIdx.x, tid = threadIdx.x;
  if (tid == 0) g_bar[b][0] = 0u;
  if (tid < HH) { h[tid]=0.f; c[tid]=0.f; }
  __syncthreads();
  for (int t=0;t<TT;t++) {
    float x0 = trend[(b*TT+t)*FF+0], x1 = trend[(b*TT+t)*FF+1];
    float gv = bih0[tid] + bhh0[tid] + x0*Wih0[tid*FF+0] + x1*Wih0[tid*FF+1];
#pragma unroll
    for (int k=0;k<HH;k++) gv += h[k]*Whh0[tid*HH+k];
    g[tid] = gv;
    __syncthreads();
    if (tid < HH) {
      float ii = sigmf(g[tid]), ff = sigmf(g[HH+tid]);
      float gg = tanhf(g[2*HH+tid]), oo = sigmf(g[3*HH+tid]);
      float cn = ff*c[tid] + ii*gg;
      c[tid] = cn;
      float hn = oo*tanhf(cn);
      h[tid] = hn;
      hs0[t][tid] = hn;
    }
    __syncthreads();
  }
  if (tid < HH) { h[tid]=0.f; c[tid]=0.f; }
  __syncthreads();
  for (int t=0;t<TT;t++) {
    float gv = bih1[tid] + bhh1[tid];
#pragma unroll
    for (int k=0;k<HH;k++) gv += hs0[t][k]*Wih1[tid*HH+k];
#pragma unroll
    for (int k=0;k<HH;k++) gv += h[k]*Whh1[tid*HH+k];
    g[tid] = gv;
    __syncthreads();
    if (tid < HH) {
      float ii = sigmf(g[tid]), ff = sigmf(g[HH+tid]);
      float gg = tanhf(g[2*HH+tid]), oo = sigmf(g[3*HH+tid]);
      float cn = ff*c[tid] + ii*gg;
      c[tid] = cn;
      h[tid] = oo*tanhf(cn);
    }
    __syncthreads();
  }
  if (tid < HH) {
    tr[tid] = h[tid];
    float fv = ffb[tid];
#pragma unroll
    for (int j=0;j<TFN;j++) fv += tfeat[b*TFN+j]*ffW[tid*TFN+j];
    fe[tid] = fmaxf(fv, 0.f);
  }
  __syncthreads();
  if (tid < FF) {
    float s = 0.f;
#pragma unroll
    for (int j=0;j<HH;j++) s += tr[j]*gcnW[tid*80+16+j];
#pragma unroll
    for (int j=0;j<HH;j++) s += fe[j]*gcnW[tid*80+48+j];
    g_c2[b*FF+tid] = s;
  }
}

// ---------------- persistent cooperative kernel: whole recurrence ----------------
struct KP {
  const float *recent, *A;
  const float *g1rW,*g1rb,*g1uW,*g1ub,*g1cW,*g1cb;
  const float *g2rW,*g2rb,*g2uW,*g2ub,*g2cW,*g2cb;
  const float *gcnW,*gcnb;
  float *out;
};

__global__ __launch_bounds__(512, 2)
void k_main(KP p){
  __shared__ __align__(16) u16 Ys[32*NN];   // 64 KB swizzled Y tile
  __shared__ float Ps [128][33];
  __shared__ float h1s[128][17];
  __shared__ float h2s[128][17];
  __shared__ float us_[128][17];
  __shared__ float rhs[128][17];

  const int wg = blockIdx.x;
  const int b = wg >> 3, i0 = (wg & 7) << 7;
  const int tid = threadIdx.x;
  const int v = tid >> 6, lane = tid & 63, m = lane & 15, quad = lane >> 4;
  const int rloc = v << 4;
  const int row = tid >> 2, jj = tid & 3;   // epilogue mapping: 4 thr/row
  const int n = i0 + row;
  const int base0 = m*2048 + ((quad ^ (m & 3)) << 4);
  const int cflip = (m >> 2) & 1;
  u32* bar = &g_bar[b][0];

  // ---- prologue: park A rows in registers (bf16), read fp32 A once ----
  bf16x8 areg[32];
  {
    const float* Ab = p.A + ((size_t)(b*NN + i0 + rloc + m))*NN + quad*8;
#pragma unroll
    for (int c=0;c<32;c++){
      float4 f0 = *(const float4*)(Ab + c*32);
      float4 f1 = *(const float4*)(Ab + c*32 + 4);
      bf16x8 tv;
      tv[0]=(short)f2bf(f0.x); tv[1]=(short)f2bf(f0.y);
      tv[2]=(short)f2bf(f0.z); tv[3]=(short)f2bf(f0.w);
      tv[4]=(short)f2bf(f1.x); tv[5]=(short)f2bf(f1.y);
      tv[6]=(short)f2bf(f1.z); tv[7]=(short)f2bf(f1.w);
      areg[c] = tv;
    }
  }

  // zero hidden state
#pragma unroll
  for (int q=0;q<4;q++){ h1s[row][jj*4+q]=0.f; h2s[row][jj*4+q]=0.f; }

  // ---- Yru1(t=0) = [rW1|uW1]·[x(0), 0]  -> buf 0 ----
  {
    const float* xr = p.recent + (((size_t)b*TT)*NN + n)*FF;
    float x0 = xr[0], x1 = xr[1];
    u16* Yb = g_Y[0][b];
#pragma unroll
    for (int m2=0;m2<8;m2++){
      int j = jj*8 + m2;
      const float* W = (j<16) ? (p.g1rW + j*18) : (p.g1uW + (j-16)*18);
      ywr(Yb, j, n, x0*W[0] + x1*W[1]);
    }
  }
  u32 gen = 0;
  bbar(bar, (++gen)*8);

  int buf = 0;
  for (int t=0;t<TT;t++){
    // ======== sweep 1: r,u cell1 (width 32) ========
    stageY<32>(g_Y[buf][b], Ys, tid);
    __syncthreads();
    {
      f32x4 a0={0.f,0.f,0.f,0.f}, a1={0.f,0.f,0.f,0.f};
      mm32(areg, Ys, base0, cflip, a0, a1);
#pragma unroll
      for (int r=0;r<4;r++){
        Ps[rloc + quad*4 + r][m]    = a0[r];
        Ps[rloc + quad*4 + r][16+m] = a1[r];
      }
    }
    __syncthreads();
#pragma unroll
    for (int q=0;q<4;q++){
      int j = jj*4+q;
      float rv = sigmf(Ps[row][j]    + p.g1rb[j]);
      float uv = sigmf(Ps[row][16+j] + p.g1ub[j]);
      us_[row][j] = uv;
      rhs[row][j] = rv * h1s[row][j];
    }
    __syncthreads();
    {
      const float* xr = p.recent + (((size_t)b*TT + t)*NN + n)*FF;
      float x0 = xr[0], x1 = xr[1];
      u16* Yb = g_Y[buf^1][b];
#pragma unroll
      for (int q=0;q<4;q++){
        int j = jj*4+q;
        const float* W = p.g1cW + j*18;
        float s = fmaf(x0, W[0], x1*W[1]);
#pragma unroll
        for (int f=0;f<16;f++) s = fmaf(rhs[row][f], W[2+f], s);
        ywr(Yb, j, n, s);
      }
    }
    bbar(bar, (++gen)*8); buf ^= 1;

    // ======== sweep 2: c cell1 -> h1; produce Yru2 (width 16) ========
    stageY<16>(g_Y[buf][b], Ys, tid);
    __syncthreads();
    {
      f32x4 a0={0.f,0.f,0.f,0.f};
      mm16(areg, Ys, base0, cflip, a0);
#pragma unroll
      for (int r=0;r<4;r++) Ps[rloc + quad*4 + r][m] = a0[r];
    }
    __syncthreads();
#pragma unroll
    for (int q=0;q<4;q++){
      int j = jj*4+q;
      float cv = tanhf(Ps[row][j] + p.g1cb[j]);
      float uv = us_[row][j];
      h1s[row][j] = uv*h1s[row][j] + (1.f-uv)*cv;
    }
    __syncthreads();
    {
      u16* Yb = g_Y[buf^1][b];
#pragma unroll
      for (int m2=0;m2<8;m2++){
        int j = jj*8 + m2;
        const float* W = (j<16) ? (p.g2rW + j*32) : (p.g2uW + (j-16)*32);
        float s = 0.f;
#pragma unroll
        for (int f=0;f<16;f++) s = fmaf(h1s[row][f], W[f],    s);
#pragma unroll
        for (int f=0;f<16;f++) s = fmaf(h2s[row][f], W[16+f], s);
        ywr(Yb, j, n, s);
      }
    }
    bbar(bar, (++gen)*8); buf ^= 1;

    // ======== sweep 3: r,u cell2 (width 32) ========
    stageY<32>(g_Y[buf][b], Ys, tid);
    __syncthreads();
    {
      f32x4 a0={0.f,0.f,0.f,0.f}, a1={0.f,0.f,0.f,0.f};
      mm32(areg, Ys, base0, cflip, a0, a1);
#pragma unroll
      for (int r=0;r<4;r++){
        Ps[rloc + quad*4 + r][m]    = a0[r];
        Ps[rloc + quad*4 + r][16+m] = a1[r];
      }
    }
    __syncthreads();
#pragma unroll
    for (int q=0;q<4;q++){
      int j = jj*4+q;
      float rv = sigmf(Ps[row][j]    + p.g2rb[j]);
      float uv = sigmf(Ps[row][16+j] + p.g2ub[j]);
      us_[row][j] = uv;
      rhs[row][j] = rv * h2s[row][j];
    }
    __syncthreads();
    {
      u16* Yb = g_Y[buf^1][b];
#pragma unroll
      for (int q=0;q<4;q++){
        int j = jj*4+q;
        const float* W = p.g2cW + j*32;
        float s = 0.f;
#pragma unroll
        for (int f=0;f<16;f++) s = fmaf(h1s[row][f], W[f],    s);
#pragma unroll
        for (int f=0;f<16;f++) s = fmaf(rhs[row][f], W[16+f], s);
        ywr(Yb, j, n, s);
      }
    }
    bbar(bar, (++gen)*8); buf ^= 1;

    // ======== sweep 4: c cell2 -> h2; Yru1(t+1) | Ysmall (width 16) ========
    stageY<16>(g_Y[buf][b], Ys, tid);
    __syncthreads();
    {
      f32x4 a0={0.f,0.f,0.f,0.f};
      mm16(areg, Ys, base0, cflip, a0);
#pragma unroll
      for (int r=0;r<4;r++) Ps[rloc + quad*4 + r][m] = a0[r];
    }
    __syncthreads();
#pragma unroll
    for (int q=0;q<4;q++){
      int j = jj*4+q;
      float cv = tanhf(Ps[row][j] + p.g2cb[j]);
      float uv = us_[row][j];
      h2s[row][j] = uv*h2s[row][j] + (1.f-uv)*cv;
    }
    __syncthreads();
    if (t < TT-1){
      const float* xr = p.recent + (((size_t)b*TT + t + 1)*NN + n)*FF;
      float x0 = xr[0], x1 = xr[1];
      u16* Yb = g_Y[buf^1][b];
#pragma unroll
      for (int m2=0;m2<8;m2++){
        int j = jj*8 + m2;
        const float* W = (j<16) ? (p.g1rW + j*18) : (p.g1uW + (j-16)*18);
        float s = fmaf(x0, W[0], x1*W[1]);
#pragma unroll
        for (int f=0;f<16;f++) s = fmaf(h1s[row][f], W[2+f], s);
        ywr(Yb, j, n, s);
      }
    } else {
      u16* Yb = g_Y[buf^1][b];
#pragma unroll
      for (int q=0;q<4;q++){
        int j = jj*4+q;
        float s = 0.f;
        if (j < FF){
          s = g_c2[b*FF + j];
#pragma unroll
          for (int f=0;f<16;f++) s = fmaf(h2s[row][f], p.gcnW[j*80+f], s);
        }
        ywr(Yb, j, n, s);
      }
    }
    bbar(bar, (++gen)*8); buf ^= 1;
  }

  // ======== final: out = tanh(A @ Ysmall + gcnb) ========
  stageY<16>(g_Y[buf][b], Ys, tid);
  __syncthreads();
  {
    f32x4 a0={0.f,0.f,0.f,0.f};
    mm16(areg, Ys, base0, cflip, a0);
    if (m < FF){
      float bb = p.gcnb[m];
#pragma unroll
      for (int r=0;r<4;r++){
        int nn = i0 + rloc + quad*4 + r;
        p.out[((size_t)b*NN + nn)*FF + m] = tanhf(a0[r] + bb);
      }
    }
  }
}

extern "C" void kernel_launch(void* const* d_in, const int* in_sizes, int n_in,
                              void* d_out, int out_size, void* d_ws, size_t ws_size,
                              hipStream_t stream) {
  (void)in_sizes; (void)n_in; (void)d_ws; (void)ws_size; (void)out_size;
  const float* recent = (const float*)d_in[0];
  const float* trend  = (const float*)d_in[1];
  const float* A      = (const float*)d_in[2];
  const float* tfeat  = (const float*)d_in[3];
  const float* g1rW = (const float*)d_in[4];  const float* g1rb = (const float*)d_in[5];
  const float* g1uW = (const float*)d_in[6];  const float* g1ub = (const float*)d_in[7];
  const float* g1cW = (const float*)d_in[8];  const float* g1cb = (const float*)d_in[9];
  const float* g2rW = (const float*)d_in[10]; const float* g2rb = (const float*)d_in[11];
  const float* g2uW = (const float*)d_in[12]; const float* g2ub = (const float*)d_in[13];
  const float* g2cW = (const float*)d_in[14]; const float* g2cb = (const float*)d_in[15];
  const float* Wih0 = (const float*)d_in[16]; const float* Whh0 = (const float*)d_in[17];
  const float* bih0 = (const float*)d_in[18]; const float* bhh0 = (const float*)d_in[19];
  const float* Wih1 = (const float*)d_in[20]; const float* Whh1 = (const float*)d_in[21];
  const float* bih1 = (const float*)d_in[22]; const float* bhh1 = (const float*)d_in[23];
  const float* ffW  = (const float*)d_in[24]; const float* ffb  = (const float*)d_in[25];
  const float* gcnW = (const float*)d_in[26]; const float* gcnb = (const float*)d_in[27];
  float* out = (float*)d_out;

  // resets per-b barrier counters + computes g_c2; ordered before k_main
  k_lstm<<<BB, 128, 0, stream>>>(trend, tfeat, Wih0, Whh0, bih0, bhh0,
                                 Wih1, Whh1, bih1, bhh1, ffW, ffb, gcnW);

  KP kp;
  kp.recent = recent; kp.A = A;
  kp.g1rW=g1rW; kp.g1rb=g1rb; kp.g1uW=g1uW; kp.g1ub=g1ub; kp.g1cW=g1cW; kp.g1cb=g1cb;
  kp.g2rW=g2rW; kp.g2rb=g2rb; kp.g2uW=g2uW; kp.g2ub=g2ub; kp.g2cW=g2cW; kp.g2cb=g2cb;
  kp.gcnW=gcnW; kp.gcnb=gcnb; kp.out=out;
  void* args[] = { (void*)&kp };
  hipLaunchCooperativeKernel((const void*)k_main, dim3(NWG), dim3(512), args, 0, stream);
}

// Round 3
// 2042.332 us; speedup vs baseline: 4.8048x; 1.9587x over previous
//
#include <hip/hip_runtime.h>
#include <cmath>
#include <stdint.h>

#define BB 32
#define TT 24
#define NN 1024
#define FF 2
#define UU 16
#define HH 32
#define TFN 31
#define NWG 256

typedef __attribute__((ext_vector_type(8))) short bf16x8;
typedef __attribute__((ext_vector_type(4))) float f32x4;
typedef unsigned short u16;
typedef unsigned int   u32;
typedef unsigned long long u64;

// Y double buffer: [2][B][32 rows][1024] bf16, bytes XOR-swizzled within each
// 2048-B row:  byte(j,k) = j*2048 + ((2k) ^ ((j&7)<<4))
// All Y traffic uses agent-scope relaxed atomics (sc1: L2-writethrough/bypass)
// so inter-WG visibility needs NO release/acquire cache maintenance.
__device__ __align__(16) u16 g_Y[2][BB][32*NN];
__device__ float g_c2[BB*FF];
// per-b barrier counters, one 256-B line each (8 arrivals per barrier)
__device__ __align__(256) u32 g_bar[BB][64];

__device__ __forceinline__ float sigmf(float x){ return 1.f/(1.f+expf(-x)); }
__device__ __forceinline__ u16 f2bf(float f){      // RNE fp32 -> bf16
  u32 u = __float_as_uint(f);
  return (u16)((u + 0x7fffu + ((u>>16)&1u)) >> 16);
}
__device__ __forceinline__ void ywr(u16* Yb, int j, int n, float s){
  u16* p = (u16*)((char*)Yb + (j<<11) + (((n<<1)) ^ ((j&7)<<4)));
  __hip_atomic_store(p, f2bf(s), __ATOMIC_RELAXED, __HIP_MEMORY_SCOPE_AGENT);
}

// ---- per-b barrier: 8 WGs of one batch; fully relaxed (no cache ops).
// __syncthreads before the RMW drains all the WG's sc1 stores (vmcnt=0 =>
// acked at the device coherence point), so count==target implies all 8 WGs'
// Y data is visible to the sc1 stage loads. Monotonic generation target.
__device__ __forceinline__ void bbar(u32* cnt, u32 target){
  __syncthreads();
  if (threadIdx.x == 0){
    __hip_atomic_fetch_add(cnt, 1u, __ATOMIC_RELAXED, __HIP_MEMORY_SCOPE_AGENT);
    while (__hip_atomic_load(cnt, __ATOMIC_RELAXED, __HIP_MEMORY_SCOPE_AGENT) < target)
      __builtin_amdgcn_s_sleep(1);
  }
  __syncthreads();
}

// ---- stage W rows (W*2048 bytes) of swizzled Y linearly into LDS ----
// 8-byte agent-relaxed loads (sc1: bypass L2, read MALL) -> LDS.
template<int W>
__device__ __forceinline__ void stageY(const u16* __restrict__ Yb, u16* Ys, int tid){
  const u64* src = (const u64*)Yb;
  u64* dst = (u64*)Ys;
#pragma unroll
  for (int q=0;q<W/2;q++){
    int idx = q*512 + tid;
    dst[idx] = __hip_atomic_load(&src[idx], __ATOMIC_RELAXED, __HIP_MEMORY_SCOPE_AGENT);
  }
}

// swizzled address decomposition: (c*64 + quad*16) ^ ((m&7)<<4)
//   = ((quad ^ (m&3))<<4) + ((c ^ ((m>>2)&1))<<6)   -> base0 + ((c^cflip)<<6)
__device__ __forceinline__ void mm32(const bf16x8 (&areg)[32], const u16* Ys,
                                     int base0, int cflip, f32x4& a0, f32x4& a1){
#pragma unroll
  for (int c=0;c<32;c++){
    int off = base0 + ((c ^ cflip) << 6);
    bf16x8 b0 = *(const bf16x8*)((const char*)Ys + off);
    bf16x8 b1 = *(const bf16x8*)((const char*)Ys + off + 32768);
    a0 = __builtin_amdgcn_mfma_f32_16x16x32_bf16(areg[c], b0, a0, 0, 0, 0);
    a1 = __builtin_amdgcn_mfma_f32_16x16x32_bf16(areg[c], b1, a1, 0, 0, 0);
  }
}
__device__ __forceinline__ void mm16(const bf16x8 (&areg)[32], const u16* Ys,
                                     int base0, int cflip, f32x4& a0){
#pragma unroll
  for (int c=0;c<32;c++){
    int off = base0 + ((c ^ cflip) << 6);
    bf16x8 b0 = *(const bf16x8*)((const char*)Ys + off);
    a0 = __builtin_amdgcn_mfma_f32_16x16x32_bf16(areg[c], b0, a0, 0, 0, 0);
  }
}

// ---------------- LSTM + ff + const2 (also resets barrier counters) ----------------
__global__ __launch_bounds__(128)
void k_lstm(const float* __restrict__ trend, const float* __restrict__ tfeat,
            const float* __restrict__ Wih0, const float* __restrict__ Whh0,
            const float* __restrict__ bih0, const float* __restrict__ bhh0,
            const float* __restrict__ Wih1, const float* __restrict__ Whh1,
            const float* __restrict__ bih1, const float* __restrict__ bhh1,
            const float* __restrict__ ffW, const float* __restrict__ ffb,
            const float* __restrict__ gcnW) {
  __shared__ float h[HH], c[HH], g[4*HH], hs0[TT][HH], tr[HH], fe[HH];
  int b = blockIdx.x, tid = threadIdx.x;
  if (tid == 0)
    __hip_atomic_store(&g_bar[b][0], 0u, __ATOMIC_RELAXED, __HIP_MEMORY_SCOPE_AGENT);
  if (tid < HH) { h[tid]=0.f; c[tid]=0.f; }
  __syncthreads();
  for (int t=0;t<TT;t++) {
    float x0 = trend[(b*TT+t)*FF+0], x1 = trend[(b*TT+t)*FF+1];
    float gv = bih0[tid] + bhh0[tid] + x0*Wih0[tid*FF+0] + x1*Wih0[tid*FF+1];
#pragma unroll
    for (int k=0;k<HH;k++) gv += h[k]*Whh0[tid*HH+k];
    g[tid] = gv;
    __syncthreads();
    if (tid < HH) {
      float ii = sigmf(g[tid]), ff = sigmf(g[HH+tid]);
      float gg = tanhf(g[2*HH+tid]), oo = sigmf(g[3*HH+tid]);
      float cn = ff*c[tid] + ii*gg;
      c[tid] = cn;
      float hn = oo*tanhf(cn);
      h[tid] = hn;
      hs0[t][tid] = hn;
    }
    __syncthreads();
  }
  if (tid < HH) { h[tid]=0.f; c[tid]=0.f; }
  __syncthreads();
  for (int t=0;t<TT;t++) {
    float gv = bih1[tid] + bhh1[tid];
#pragma unroll
    for (int k=0;k<HH;k++) gv += hs0[t][k]*Wih1[tid*HH+k];
#pragma unroll
    for (int k=0;k<HH;k++) gv += h[k]*Whh1[tid*HH+k];
    g[tid] = gv;
    __syncthreads();
    if (tid < HH) {
      float ii = sigmf(g[tid]), ff = sigmf(g[HH+tid]);
      float gg = tanhf(g[2*HH+tid]), oo = sigmf(g[3*HH+tid]);
      float cn = ff*c[tid] + ii*gg;
      c[tid] = cn;
      h[tid] = oo*tanhf(cn);
    }
    __syncthreads();
  }
  if (tid < HH) {
    tr[tid] = h[tid];
    float fv = ffb[tid];
#pragma unroll
    for (int j=0;j<TFN;j++) fv += tfeat[b*TFN+j]*ffW[tid*TFN+j];
    fe[tid] = fmaxf(fv, 0.f);
  }
  __syncthreads();
  if (tid < FF) {
    float s = 0.f;
#pragma unroll
    for (int j=0;j<HH;j++) s += tr[j]*gcnW[tid*80+16+j];
#pragma unroll
    for (int j=0;j<HH;j++) s += fe[j]*gcnW[tid*80+48+j];
    g_c2[b*FF+tid] = s;
  }
}

// ---------------- persistent cooperative kernel: whole recurrence ----------------
struct KP {
  const float *recent, *A;
  const float *g1rW,*g1rb,*g1uW,*g1ub,*g1cW,*g1cb;
  const float *g2rW,*g2rb,*g2uW,*g2ub,*g2cW,*g2cb;
  const float *gcnW,*gcnb;
  float *out;
};

__global__ __launch_bounds__(512, 2)
void k_main(KP p){
  __shared__ __align__(16) u16 Ys[32*NN];   // 64 KB swizzled Y tile
  __shared__ float Ps [128][33];
  __shared__ float h1s[128][17];
  __shared__ float h2s[128][17];
  __shared__ float us_[128][17];
  __shared__ float rhs[128][17];

  const int wg = blockIdx.x;
  const int b = wg >> 3, i0 = (wg & 7) << 7;
  const int tid = threadIdx.x;
  const int v = tid >> 6, lane = tid & 63, m = lane & 15, quad = lane >> 4;
  const int rloc = v << 4;
  const int row = tid >> 2, jj = tid & 3;   // epilogue mapping: 4 thr/row
  const int n = i0 + row;
  const int base0 = m*2048 + ((quad ^ (m & 3)) << 4);
  const int cflip = (m >> 2) & 1;
  u32* bar = &g_bar[b][0];

  // ---- prologue: park A rows in registers (bf16), read fp32 A once ----
  bf16x8 areg[32];
  {
    const float* Ab = p.A + ((size_t)(b*NN + i0 + rloc + m))*NN + quad*8;
#pragma unroll
    for (int c=0;c<32;c++){
      float4 f0 = *(const float4*)(Ab + c*32);
      float4 f1 = *(const float4*)(Ab + c*32 + 4);
      bf16x8 tv;
      tv[0]=(short)f2bf(f0.x); tv[1]=(short)f2bf(f0.y);
      tv[2]=(short)f2bf(f0.z); tv[3]=(short)f2bf(f0.w);
      tv[4]=(short)f2bf(f1.x); tv[5]=(short)f2bf(f1.y);
      tv[6]=(short)f2bf(f1.z); tv[7]=(short)f2bf(f1.w);
      areg[c] = tv;
    }
  }

  // zero hidden state
#pragma unroll
  for (int q=0;q<4;q++){ h1s[row][jj*4+q]=0.f; h2s[row][jj*4+q]=0.f; }

  // ---- Yru1(t=0) = [rW1|uW1]·[x(0), 0]  -> buf 0 ----
  {
    const float* xr = p.recent + (((size_t)b*TT)*NN + n)*FF;
    float x0 = xr[0], x1 = xr[1];
    u16* Yb = g_Y[0][b];
#pragma unroll
    for (int m2=0;m2<8;m2++){
      int j = jj*8 + m2;
      const float* W = (j<16) ? (p.g1rW + j*18) : (p.g1uW + (j-16)*18);
      ywr(Yb, j, n, x0*W[0] + x1*W[1]);
    }
  }
  u32 gen = 0;
  bbar(bar, (++gen)*8);

  int buf = 0;
  for (int t=0;t<TT;t++){
    // ======== sweep 1: r,u cell1 (width 32) ========
    stageY<32>(g_Y[buf][b], Ys, tid);
    __syncthreads();
    {
      f32x4 a0={0.f,0.f,0.f,0.f}, a1={0.f,0.f,0.f,0.f};
      mm32(areg, Ys, base0, cflip, a0, a1);
#pragma unroll
      for (int r=0;r<4;r++){
        Ps[rloc + quad*4 + r][m]    = a0[r];
        Ps[rloc + quad*4 + r][16+m] = a1[r];
      }
    }
    __syncthreads();
#pragma unroll
    for (int q=0;q<4;q++){
      int j = jj*4+q;
      float rv = sigmf(Ps[row][j]    + p.g1rb[j]);
      float uv = sigmf(Ps[row][16+j] + p.g1ub[j]);
      us_[row][j] = uv;
      rhs[row][j] = rv * h1s[row][j];
    }
    __syncthreads();
    {
      const float* xr = p.recent + (((size_t)b*TT + t)*NN + n)*FF;
      float x0 = xr[0], x1 = xr[1];
      u16* Yb = g_Y[buf^1][b];
#pragma unroll
      for (int q=0;q<4;q++){
        int j = jj*4+q;
        const float* W = p.g1cW + j*18;
        float s = fmaf(x0, W[0], x1*W[1]);
#pragma unroll
        for (int f=0;f<16;f++) s = fmaf(rhs[row][f], W[2+f], s);
        ywr(Yb, j, n, s);
      }
    }
    bbar(bar, (++gen)*8); buf ^= 1;

    // ======== sweep 2: c cell1 -> h1; produce Yru2 (width 16) ========
    stageY<16>(g_Y[buf][b], Ys, tid);
    __syncthreads();
    {
      f32x4 a0={0.f,0.f,0.f,0.f};
      mm16(areg, Ys, base0, cflip, a0);
#pragma unroll
      for (int r=0;r<4;r++) Ps[rloc + quad*4 + r][m] = a0[r];
    }
    __syncthreads();
#pragma unroll
    for (int q=0;q<4;q++){
      int j = jj*4+q;
      float cv = tanhf(Ps[row][j] + p.g1cb[j]);
      float uv = us_[row][j];
      h1s[row][j] = uv*h1s[row][j] + (1.f-uv)*cv;
    }
    __syncthreads();
    {
      u16* Yb = g_Y[buf^1][b];
#pragma unroll
      for (int m2=0;m2<8;m2++){
        int j = jj*8 + m2;
        const float* W = (j<16) ? (p.g2rW + j*32) : (p.g2uW + (j-16)*32);
        float s = 0.f;
#pragma unroll
        for (int f=0;f<16;f++) s = fmaf(h1s[row][f], W[f],    s);
#pragma unroll
        for (int f=0;f<16;f++) s = fmaf(h2s[row][f], W[16+f], s);
        ywr(Yb, j, n, s);
      }
    }
    bbar(bar, (++gen)*8); buf ^= 1;

    // ======== sweep 3: r,u cell2 (width 32) ========
    stageY<32>(g_Y[buf][b], Ys, tid);
    __syncthreads();
    {
      f32x4 a0={0.f,0.f,0.f,0.f}, a1={0.f,0.f,0.f,0.f};
      mm32(areg, Ys, base0, cflip, a0, a1);
#pragma unroll
      for (int r=0;r<4;r++){
        Ps[rloc + quad*4 + r][m]    = a0[r];
        Ps[rloc + quad*4 + r][16+m] = a1[r];
      }
    }
    __syncthreads();
#pragma unroll
    for (int q=0;q<4;q++){
      int j = jj*4+q;
      float rv = sigmf(Ps[row][j]    + p.g2rb[j]);
      float uv = sigmf(Ps[row][16+j] + p.g2ub[j]);
      us_[row][j] = uv;
      rhs[row][j] = rv * h2s[row][j];
    }
    __syncthreads();
    {
      u16* Yb = g_Y[buf^1][b];
#pragma unroll
      for (int q=0;q<4;q++){
        int j = jj*4+q;
        const float* W = p.g2cW + j*32;
        float s = 0.f;
#pragma unroll
        for (int f=0;f<16;f++) s = fmaf(h1s[row][f], W[f],    s);
#pragma unroll
        for (int f=0;f<16;f++) s = fmaf(rhs[row][f], W[16+f], s);
        ywr(Yb, j, n, s);
      }
    }
    bbar(bar, (++gen)*8); buf ^= 1;

    // ======== sweep 4: c cell2 -> h2; Yru1(t+1) | Ysmall (width 16) ========
    stageY<16>(g_Y[buf][b], Ys, tid);
    __syncthreads();
    {
      f32x4 a0={0.f,0.f,0.f,0.f};
      mm16(areg, Ys, base0, cflip, a0);
#pragma unroll
      for (int r=0;r<4;r++) Ps[rloc + quad*4 + r][m] = a0[r];
    }
    __syncthreads();
#pragma unroll
    for (int q=0;q<4;q++){
      int j = jj*4+q;
      float cv = tanhf(Ps[row][j] + p.g2cb[j]);
      float uv = us_[row][j];
      h2s[row][j] = uv*h2s[row][j] + (1.f-uv)*cv;
    }
    __syncthreads();
    if (t < TT-1){
      const float* xr = p.recent + (((size_t)b*TT + t + 1)*NN + n)*FF;
      float x0 = xr[0], x1 = xr[1];
      u16* Yb = g_Y[buf^1][b];
#pragma unroll
      for (int m2=0;m2<8;m2++){
        int j = jj*8 + m2;
        const float* W = (j<16) ? (p.g1rW + j*18) : (p.g1uW + (j-16)*18);
        float s = fmaf(x0, W[0], x1*W[1]);
#pragma unroll
        for (int f=0;f<16;f++) s = fmaf(h1s[row][f], W[2+f], s);
        ywr(Yb, j, n, s);
      }
    } else {
      u16* Yb = g_Y[buf^1][b];
#pragma unroll
      for (int q=0;q<4;q++){
        int j = jj*4+q;
        float s = 0.f;
        if (j < FF){
          s = g_c2[b*FF + j];
#pragma unroll
          for (int f=0;f<16;f++) s = fmaf(h2s[row][f], p.gcnW[j*80+f], s);
        }
        ywr(Yb, j, n, s);
      }
    }
    bbar(bar, (++gen)*8); buf ^= 1;
  }

  // ======== final: out = tanh(A @ Ysmall + gcnb) ========
  stageY<16>(g_Y[buf][b], Ys, tid);
  __syncthreads();
  {
    f32x4 a0={0.f,0.f,0.f,0.f};
    mm16(areg, Ys, base0, cflip, a0);
    if (m < FF){
      float bb = p.gcnb[m];
#pragma unroll
      for (int r=0;r<4;r++){
        int nn = i0 + rloc + quad*4 + r;
        p.out[((size_t)b*NN + nn)*FF + m] = tanhf(a0[r] + bb);
      }
    }
  }
}

extern "C" void kernel_launch(void* const* d_in, const int* in_sizes, int n_in,
                              void* d_out, int out_size, void* d_ws, size_t ws_size,
                              hipStream_t stream) {
  (void)in_sizes; (void)n_in; (void)d_ws; (void)ws_size; (void)out_size;
  const float* recent = (const float*)d_in[0];
  const float* trend  = (const float*)d_in[1];
  const float* A      = (const float*)d_in[2];
  const float* tfeat  = (const float*)d_in[3];
  const float* g1rW = (const float*)d_in[4];  const float* g1rb = (const float*)d_in[5];
  const float* g1uW = (const float*)d_in[6];  const float* g1ub = (const float*)d_in[7];
  const float* g1cW = (const float*)d_in[8];  const float* g1cb = (const float*)d_in[9];
  const float* g2rW = (const float*)d_in[10]; const float* g2rb = (const float*)d_in[11];
  const float* g2uW = (const float*)d_in[12]; const float* g2ub = (const float*)d_in[13];
  const float* g2cW = (const float*)d_in[14]; const float* g2cb = (const float*)d_in[15];
  const float* Wih0 = (const float*)d_in[16]; const float* Whh0 = (const float*)d_in[17];
  const float* bih0 = (const float*)d_in[18]; const float* bhh0 = (const float*)d_in[19];
  const float* Wih1 = (const float*)d_in[20]; const float* Whh1 = (const float*)d_in[21];
  const float* bih1 = (const float*)d_in[22]; const float* bhh1 = (const float*)d_in[23];
  const float* ffW  = (const float*)d_in[24]; const float* ffb  = (const float*)d_in[25];
  const float* gcnW = (const float*)d_in[26]; const float* gcnb = (const float*)d_in[27];
  float* out = (float*)d_out;

  // resets per-b barrier counters + computes g_c2; ordered before k_main
  k_lstm<<<BB, 128, 0, stream>>>(trend, tfeat, Wih0, Whh0, bih0, bhh0,
                                 Wih1, Whh1, bih1, bhh1, ffW, ffb, gcnW);

  KP kp;
  kp.recent = recent; kp.A = A;
  kp.g1rW=g1rW; kp.g1rb=g1rb; kp.g1uW=g1uW; kp.g1ub=g1ub; kp.g1cW=g1cW; kp.g1cb=g1cb;
  kp.g2rW=g2rW; kp.g2rb=g2rb; kp.g2uW=g2uW; kp.g2ub=g2ub; kp.g2cW=g2cW; kp.g2cb=g2cb;
  kp.gcnW=gcnW; kp.gcnb=gcnb; kp.out=out;
  void* args[] = { (void*)&kp };
  hipLaunchCooperativeKernel((const void*)k_main, dim3(NWG), dim3(512), args, 0, stream);
}

// Round 4
// 1604.706 us; speedup vs baseline: 6.1151x; 1.2727x over previous
//
#include <hip/hip_runtime.h>
#include <cmath>
#include <stdint.h>

#define BB 32
#define TT 24
#define NN 1024
#define FF 2
#define UU 16
#define HH 32
#define TFN 31
#define NWG 256

typedef __attribute__((ext_vector_type(8))) short bf16x8;
typedef __attribute__((ext_vector_type(4))) float f32x4;
typedef unsigned short u16;
typedef unsigned int   u32;
typedef __attribute__((ext_vector_type(4))) u32 u32x4;

// Y double buffer: [2][B][32 rows][1024] bf16, bytes XOR-swizzled within each
// 2048-B row:  byte(j,k) = j*2048 + ((2k) ^ ((j&7)<<4))
// Coherence protocol is chosen PER BATCH-GROUP at runtime:
//  mode A (all 8 WGs of the batch on one XCD): normal stores -> shared L2;
//          sc0 (L1-bypass) loads read the shared L2. No cache maintenance.
//  mode B (split placement): sc1 device-coherent stores + sc0 sc1 loads (MALL).
__device__ __align__(16) u16 g_Y[2][BB][32*NN];
__device__ float g_c2[BB*FF];
// per-b barrier counters, one 256-B line each (8 arrivals per barrier)
__device__ __align__(256) u32 g_bar[BB][64];
__device__ u32 g_xcdmask[BB];

__device__ __forceinline__ float sigmf(float x){ return 1.f/(1.f+expf(-x)); }
__device__ __forceinline__ u16 f2bf(float f){      // RNE fp32 -> bf16
  u32 u = __float_as_uint(f);
  return (u16)((u + 0x7fffu + ((u>>16)&1u)) >> 16);
}
// modeA: plain store (write-through L1 -> lands in this XCD's L2).
// modeB: agent-relaxed store (sc1: write through to MALL).
__device__ __forceinline__ void ywr(u16* Yb, int j, int n, float s, bool modeA){
  u16* p = (u16*)((char*)Yb + (j<<11) + (((n<<1)) ^ ((j&7)<<4)));
  u16 v = f2bf(s);
  if (modeA) *p = v;
  else __hip_atomic_store(p, v, __ATOMIC_RELAXED, __HIP_MEMORY_SCOPE_AGENT);
}

// ---- per-b barrier: 8 WGs of one batch; fully relaxed MALL counter (no cache
// ops, placement-independent). __syncthreads before the RMW drains vmcnt ->
// all the WG's Y stores are committed (L2 for mode A, MALL for mode B) before
// the arrival is visible. Monotonic generation target.
__device__ __forceinline__ void bbar(u32* cnt, u32 target){
  __syncthreads();
  if (threadIdx.x == 0){
    __hip_atomic_fetch_add(cnt, 1u, __ATOMIC_RELAXED, __HIP_MEMORY_SCOPE_AGENT);
    while (__hip_atomic_load(cnt, __ATOMIC_RELAXED, __HIP_MEMORY_SCOPE_AGENT) < target)
      __builtin_amdgcn_s_sleep(1);
  }
  __syncthreads();
}

// ---- stage W rows (W*2048 bytes) of swizzled Y linearly into LDS ----
// 16-B loads; mode A: sc0 (bypass L1, read shared L2). mode B: sc0 sc1 (MALL).
template<int W>
__device__ __forceinline__ void stageY(const u16* __restrict__ Yb, u16* Ys,
                                       int tid, bool modeA){
  u32x4 r[W/4];
  if (modeA){
#pragma unroll
    for (int q=0;q<W/4;q++){
      const char* src = (const char*)Yb + q*8192 + tid*16;
      asm volatile("global_load_dwordx4 %0, %1, off sc0"
                   : "=v"(r[q]) : "v"(src));
    }
  } else {
#pragma unroll
    for (int q=0;q<W/4;q++){
      const char* src = (const char*)Yb + q*8192 + tid*16;
      asm volatile("global_load_dwordx4 %0, %1, off sc0 sc1"
                   : "=v"(r[q]) : "v"(src));
    }
  }
  asm volatile("s_waitcnt vmcnt(0)" ::: "memory");
  __builtin_amdgcn_sched_barrier(0);
#pragma unroll
  for (int q=0;q<W/4;q++)
    *(u32x4*)((char*)Ys + q*8192 + tid*16) = r[q];
}

// swizzled address decomposition: (c*64 + quad*16) ^ ((m&7)<<4)
//   = ((quad ^ (m&3))<<4) + ((c ^ ((m>>2)&1))<<6)   -> base0 + ((c^cflip)<<6)
__device__ __forceinline__ void mm32(const bf16x8 (&areg)[32], const u16* Ys,
                                     int base0, int cflip, f32x4& a0, f32x4& a1){
#pragma unroll
  for (int c=0;c<32;c++){
    int off = base0 + ((c ^ cflip) << 6);
    bf16x8 b0 = *(const bf16x8*)((const char*)Ys + off);
    bf16x8 b1 = *(const bf16x8*)((const char*)Ys + off + 32768);
    a0 = __builtin_amdgcn_mfma_f32_16x16x32_bf16(areg[c], b0, a0, 0, 0, 0);
    a1 = __builtin_amdgcn_mfma_f32_16x16x32_bf16(areg[c], b1, a1, 0, 0, 0);
  }
}
__device__ __forceinline__ void mm16(const bf16x8 (&areg)[32], const u16* Ys,
                                     int base0, int cflip, f32x4& a0){
#pragma unroll
  for (int c=0;c<32;c++){
    int off = base0 + ((c ^ cflip) << 6);
    bf16x8 b0 = *(const bf16x8*)((const char*)Ys + off);
    a0 = __builtin_amdgcn_mfma_f32_16x16x32_bf16(areg[c], b0, a0, 0, 0, 0);
  }
}

// ---------------- LSTM + ff + const2 (also resets barrier/mask) ----------------
__global__ __launch_bounds__(128)
void k_lstm(const float* __restrict__ trend, const float* __restrict__ tfeat,
            const float* __restrict__ Wih0, const float* __restrict__ Whh0,
            const float* __restrict__ bih0, const float* __restrict__ bhh0,
            const float* __restrict__ Wih1, const float* __restrict__ Whh1,
            const float* __restrict__ bih1, const float* __restrict__ bhh1,
            const float* __restrict__ ffW, const float* __restrict__ ffb,
            const float* __restrict__ gcnW) {
  __shared__ float h[HH], c[HH], g[4*HH], hs0[TT][HH], tr[HH], fe[HH];
  int b = blockIdx.x, tid = threadIdx.x;
  if (tid == 0){
    __hip_atomic_store(&g_bar[b][0], 0u, __ATOMIC_RELAXED, __HIP_MEMORY_SCOPE_AGENT);
    __hip_atomic_store(&g_xcdmask[b], 0u, __ATOMIC_RELAXED, __HIP_MEMORY_SCOPE_AGENT);
  }
  if (tid < HH) { h[tid]=0.f; c[tid]=0.f; }
  __syncthreads();
  for (int t=0;t<TT;t++) {
    float x0 = trend[(b*TT+t)*FF+0], x1 = trend[(b*TT+t)*FF+1];
    float gv = bih0[tid] + bhh0[tid] + x0*Wih0[tid*FF+0] + x1*Wih0[tid*FF+1];
#pragma unroll
    for (int k=0;k<HH;k++) gv += h[k]*Whh0[tid*HH+k];
    g[tid] = gv;
    __syncthreads();
    if (tid < HH) {
      float ii = sigmf(g[tid]), ff = sigmf(g[HH+tid]);
      float gg = tanhf(g[2*HH+tid]), oo = sigmf(g[3*HH+tid]);
      float cn = ff*c[tid] + ii*gg;
      c[tid] = cn;
      float hn = oo*tanhf(cn);
      h[tid] = hn;
      hs0[t][tid] = hn;
    }
    __syncthreads();
  }
  if (tid < HH) { h[tid]=0.f; c[tid]=0.f; }
  __syncthreads();
  for (int t=0;t<TT;t++) {
    float gv = bih1[tid] + bhh1[tid];
#pragma unroll
    for (int k=0;k<HH;k++) gv += hs0[t][k]*Wih1[tid*HH+k];
#pragma unroll
    for (int k=0;k<HH;k++) gv += h[k]*Whh1[tid*HH+k];
    g[tid] = gv;
    __syncthreads();
    if (tid < HH) {
      float ii = sigmf(g[tid]), ff = sigmf(g[HH+tid]);
      float gg = tanhf(g[2*HH+tid]), oo = sigmf(g[3*HH+tid]);
      float cn = ff*c[tid] + ii*gg;
      c[tid] = cn;
      h[tid] = oo*tanhf(cn);
    }
    __syncthreads();
  }
  if (tid < HH) {
    tr[tid] = h[tid];
    float fv = ffb[tid];
#pragma unroll
    for (int j=0;j<TFN;j++) fv += tfeat[b*TFN+j]*ffW[tid*TFN+j];
    fe[tid] = fmaxf(fv, 0.f);
  }
  __syncthreads();
  if (tid < FF) {
    float s = 0.f;
#pragma unroll
    for (int j=0;j<HH;j++) s += tr[j]*gcnW[tid*80+16+j];
#pragma unroll
    for (int j=0;j<HH;j++) s += fe[j]*gcnW[tid*80+48+j];
    g_c2[b*FF+tid] = s;
  }
}

// ---------------- persistent cooperative kernel: whole recurrence ----------------
struct KP {
  const float *recent, *A;
  const float *g1rW,*g1rb,*g1uW,*g1ub,*g1cW,*g1cb;
  const float *g2rW,*g2rb,*g2uW,*g2ub,*g2cW,*g2cb;
  const float *gcnW,*gcnb;
  float *out;
};

__global__ __launch_bounds__(512, 2)
void k_main(KP p){
  __shared__ __align__(16) u16 Ys[32*NN];   // 64 KB swizzled Y tile
  __shared__ float Ps [128][33];
  __shared__ float h1s[128][17];
  __shared__ float h2s[128][17];
  __shared__ float us_[128][17];
  __shared__ float rhs[128][17];

  const int wg = blockIdx.x;
  // XCD-grouped work mapping (round-robin dispatch: WGs {x, x+8, ...} share
  // XCD x). XCD x owns batches x*4 .. x*4+3, 8 row-chunks each.
  const int b = (wg & 7)*4 + (wg >> 6);
  const int i0 = ((wg >> 3) & 7) << 7;
  const int tid = threadIdx.x;
  const int v = tid >> 6, lane = tid & 63, m = lane & 15, quad = lane >> 4;
  const int rloc = v << 4;
  const int row = tid >> 2, jj = tid & 3;   // epilogue mapping: 4 thr/row
  const int n = i0 + row;
  const int base0 = m*2048 + ((quad ^ (m & 3)) << 4);
  const int cflip = (m >> 2) & 1;
  u32* bar = &g_bar[b][0];

  // publish this WG's XCD id for the group placement check
  if (tid == 0){
    u32 xcc;
    asm volatile("s_getreg_b32 %0, hwreg(HW_REG_XCC_ID)" : "=s"(xcc));
    __hip_atomic_fetch_or(&g_xcdmask[b], 1u << (xcc & 31),
                          __ATOMIC_RELAXED, __HIP_MEMORY_SCOPE_AGENT);
  }

  // ---- prologue: park A rows in registers (bf16), read fp32 A once ----
  bf16x8 areg[32];
  {
    const float* Ab = p.A + ((size_t)(b*NN + i0 + rloc + m))*NN + quad*8;
#pragma unroll
    for (int c=0;c<32;c++){
      float4 f0 = *(const float4*)(Ab + c*32);
      float4 f1 = *(const float4*)(Ab + c*32 + 4);
      bf16x8 tv;
      tv[0]=(short)f2bf(f0.x); tv[1]=(short)f2bf(f0.y);
      tv[2]=(short)f2bf(f0.z); tv[3]=(short)f2bf(f0.w);
      tv[4]=(short)f2bf(f1.x); tv[5]=(short)f2bf(f1.y);
      tv[6]=(short)f2bf(f1.z); tv[7]=(short)f2bf(f1.w);
      areg[c] = tv;
    }
  }

  // zero hidden state
#pragma unroll
  for (int q=0;q<4;q++){ h1s[row][jj*4+q]=0.f; h2s[row][jj*4+q]=0.f; }

  // ---- Yru1(t=0): mode unknown yet -> device-coherent (mode B) writes ----
  {
    const float* xr = p.recent + (((size_t)b*TT)*NN + n)*FF;
    float x0 = xr[0], x1 = xr[1];
    u16* Yb = g_Y[0][b];
#pragma unroll
    for (int m2=0;m2<8;m2++){
      int j = jj*8 + m2;
      const float* W = (j<16) ? (p.g1rW + j*18) : (p.g1uW + (j-16)*18);
      ywr(Yb, j, n, x0*W[0] + x1*W[1], false);
    }
  }
  u32 gen = 0;
  bbar(bar, (++gen)*8);

  // group placement decision (uniform across the 8 WGs of this batch)
  const u32 mk = __hip_atomic_load(&g_xcdmask[b], __ATOMIC_RELAXED,
                                   __HIP_MEMORY_SCOPE_AGENT);
  const bool modeA = (__popc(mk) == 1);

  int buf = 0;
  for (int t=0;t<TT;t++){
    // ======== sweep 1: r,u cell1 (width 32) ========
    stageY<32>(g_Y[buf][b], Ys, tid, modeA);
    __syncthreads();
    {
      f32x4 a0={0.f,0.f,0.f,0.f}, a1={0.f,0.f,0.f,0.f};
      mm32(areg, Ys, base0, cflip, a0, a1);
#pragma unroll
      for (int r=0;r<4;r++){
        Ps[rloc + quad*4 + r][m]    = a0[r];
        Ps[rloc + quad*4 + r][16+m] = a1[r];
      }
    }
    __syncthreads();
#pragma unroll
    for (int q=0;q<4;q++){
      int j = jj*4+q;
      float rv = sigmf(Ps[row][j]    + p.g1rb[j]);
      float uv = sigmf(Ps[row][16+j] + p.g1ub[j]);
      us_[row][j] = uv;
      rhs[row][j] = rv * h1s[row][j];
    }
    __syncthreads();
    {
      const float* xr = p.recent + (((size_t)b*TT + t)*NN + n)*FF;
      float x0 = xr[0], x1 = xr[1];
      u16* Yb = g_Y[buf^1][b];
#pragma unroll
      for (int q=0;q<4;q++){
        int j = jj*4+q;
        const float* W = p.g1cW + j*18;
        float s = fmaf(x0, W[0], x1*W[1]);
#pragma unroll
        for (int f=0;f<16;f++) s = fmaf(rhs[row][f], W[2+f], s);
        ywr(Yb, j, n, s, modeA);
      }
    }
    bbar(bar, (++gen)*8); buf ^= 1;

    // ======== sweep 2: c cell1 -> h1; produce Yru2 (width 16) ========
    stageY<16>(g_Y[buf][b], Ys, tid, modeA);
    __syncthreads();
    {
      f32x4 a0={0.f,0.f,0.f,0.f};
      mm16(areg, Ys, base0, cflip, a0);
#pragma unroll
      for (int r=0;r<4;r++) Ps[rloc + quad*4 + r][m] = a0[r];
    }
    __syncthreads();
#pragma unroll
    for (int q=0;q<4;q++){
      int j = jj*4+q;
      float cv = tanhf(Ps[row][j] + p.g1cb[j]);
      float uv = us_[row][j];
      h1s[row][j] = uv*h1s[row][j] + (1.f-uv)*cv;
    }
    __syncthreads();
    {
      u16* Yb = g_Y[buf^1][b];
#pragma unroll
      for (int m2=0;m2<8;m2++){
        int j = jj*8 + m2;
        const float* W = (j<16) ? (p.g2rW + j*32) : (p.g2uW + (j-16)*32);
        float s = 0.f;
#pragma unroll
        for (int f=0;f<16;f++) s = fmaf(h1s[row][f], W[f],    s);
#pragma unroll
        for (int f=0;f<16;f++) s = fmaf(h2s[row][f], W[16+f], s);
        ywr(Yb, j, n, s, modeA);
      }
    }
    bbar(bar, (++gen)*8); buf ^= 1;

    // ======== sweep 3: r,u cell2 (width 32) ========
    stageY<32>(g_Y[buf][b], Ys, tid, modeA);
    __syncthreads();
    {
      f32x4 a0={0.f,0.f,0.f,0.f}, a1={0.f,0.f,0.f,0.f};
      mm32(areg, Ys, base0, cflip, a0, a1);
#pragma unroll
      for (int r=0;r<4;r++){
        Ps[rloc + quad*4 + r][m]    = a0[r];
        Ps[rloc + quad*4 + r][16+m] = a1[r];
      }
    }
    __syncthreads();
#pragma unroll
    for (int q=0;q<4;q++){
      int j = jj*4+q;
      float rv = sigmf(Ps[row][j]    + p.g2rb[j]);
      float uv = sigmf(Ps[row][16+j] + p.g2ub[j]);
      us_[row][j] = uv;
      rhs[row][j] = rv * h2s[row][j];
    }
    __syncthreads();
    {
      u16* Yb = g_Y[buf^1][b];
#pragma unroll
      for (int q=0;q<4;q++){
        int j = jj*4+q;
        const float* W = p.g2cW + j*32;
        float s = 0.f;
#pragma unroll
        for (int f=0;f<16;f++) s = fmaf(h1s[row][f], W[f],    s);
#pragma unroll
        for (int f=0;f<16;f++) s = fmaf(rhs[row][f], W[16+f], s);
        ywr(Yb, j, n, s, modeA);
      }
    }
    bbar(bar, (++gen)*8); buf ^= 1;

    // ======== sweep 4: c cell2 -> h2; Yru1(t+1) | Ysmall (width 16) ========
    stageY<16>(g_Y[buf][b], Ys, tid, modeA);
    __syncthreads();
    {
      f32x4 a0={0.f,0.f,0.f,0.f};
      mm16(areg, Ys, base0, cflip, a0);
#pragma unroll
      for (int r=0;r<4;r++) Ps[rloc + quad*4 + r][m] = a0[r];
    }
    __syncthreads();
#pragma unroll
    for (int q=0;q<4;q++){
      int j = jj*4+q;
      float cv = tanhf(Ps[row][j] + p.g2cb[j]);
      float uv = us_[row][j];
      h2s[row][j] = uv*h2s[row][j] + (1.f-uv)*cv;
    }
    __syncthreads();
    if (t < TT-1){
      const float* xr = p.recent + (((size_t)b*TT + t + 1)*NN + n)*FF;
      float x0 = xr[0], x1 = xr[1];
      u16* Yb = g_Y[buf^1][b];
#pragma unroll
      for (int m2=0;m2<8;m2++){
        int j = jj*8 + m2;
        const float* W = (j<16) ? (p.g1rW + j*18) : (p.g1uW + (j-16)*18);
        float s = fmaf(x0, W[0], x1*W[1]);
#pragma unroll
        for (int f=0;f<16;f++) s = fmaf(h1s[row][f], W[2+f], s);
        ywr(Yb, j, n, s, modeA);
      }
    } else {
      u16* Yb = g_Y[buf^1][b];
#pragma unroll
      for (int q=0;q<4;q++){
        int j = jj*4+q;
        float s = 0.f;
        if (j < FF){
          s = g_c2[b*FF + j];
#pragma unroll
          for (int f=0;f<16;f++) s = fmaf(h2s[row][f], p.gcnW[j*80+f], s);
        }
        ywr(Yb, j, n, s, modeA);
      }
    }
    bbar(bar, (++gen)*8); buf ^= 1;
  }

  // ======== final: out = tanh(A @ Ysmall + gcnb) ========
  stageY<16>(g_Y[buf][b], Ys, tid, modeA);
  __syncthreads();
  {
    f32x4 a0={0.f,0.f,0.f,0.f};
    mm16(areg, Ys, base0, cflip, a0);
    if (m < FF){
      float bb = p.gcnb[m];
#pragma unroll
      for (int r=0;r<4;r++){
        int nn = i0 + rloc + quad*4 + r;
        p.out[((size_t)b*NN + nn)*FF + m] = tanhf(a0[r] + bb);
      }
    }
  }
}

extern "C" void kernel_launch(void* const* d_in, const int* in_sizes, int n_in,
                              void* d_out, int out_size, void* d_ws, size_t ws_size,
                              hipStream_t stream) {
  (void)in_sizes; (void)n_in; (void)d_ws; (void)ws_size; (void)out_size;
  const float* recent = (const float*)d_in[0];
  const float* trend  = (const float*)d_in[1];
  const float* A      = (const float*)d_in[2];
  const float* tfeat  = (const float*)d_in[3];
  const float* g1rW = (const float*)d_in[4];  const float* g1rb = (const float*)d_in[5];
  const float* g1uW = (const float*)d_in[6];  const float* g1ub = (const float*)d_in[7];
  const float* g1cW = (const float*)d_in[8];  const float* g1cb = (const float*)d_in[9];
  const float* g2rW = (const float*)d_in[10]; const float* g2rb = (const float*)d_in[11];
  const float* g2uW = (const float*)d_in[12]; const float* g2ub = (const float*)d_in[13];
  const float* g2cW = (const float*)d_in[14]; const float* g2cb = (const float*)d_in[15];
  const float* Wih0 = (const float*)d_in[16]; const float* Whh0 = (const float*)d_in[17];
  const float* bih0 = (const float*)d_in[18]; const float* bhh0 = (const float*)d_in[19];
  const float* Wih1 = (const float*)d_in[20]; const float* Whh1 = (const float*)d_in[21];
  const float* bih1 = (const float*)d_in[22]; const float* bhh1 = (const float*)d_in[23];
  const float* ffW  = (const float*)d_in[24]; const float* ffb  = (const float*)d_in[25];
  const float* gcnW = (const float*)d_in[26]; const float* gcnb = (const float*)d_in[27];
  float* out = (float*)d_out;

  // resets per-b barrier counters + placement masks + computes g_c2
  k_lstm<<<BB, 128, 0, stream>>>(trend, tfeat, Wih0, Whh0, bih0, bhh0,
                                 Wih1, Whh1, bih1, bhh1, ffW, ffb, gcnW);

  KP kp;
  kp.recent = recent; kp.A = A;
  kp.g1rW=g1rW; kp.g1rb=g1rb; kp.g1uW=g1uW; kp.g1ub=g1ub; kp.g1cW=g1cW; kp.g1cb=g1cb;
  kp.g2rW=g2rW; kp.g2rb=g2rb; kp.g2uW=g2uW; kp.g2ub=g2ub; kp.g2cW=g2cW; kp.g2cb=g2cb;
  kp.gcnW=gcnW; kp.gcnb=gcnb; kp.out=out;
  void* args[] = { (void*)&kp };
  hipLaunchCooperativeKernel((const void*)k_main, dim3(NWG), dim3(512), args, 0, stream);
}